// Round 1
// baseline (403.779 us; speedup 1.0000x reference)
//
#include <hip/hip_runtime.h>

typedef float f32x4 __attribute__((ext_vector_type(4)));

static constexpr int E_ = 8, M_ = 4096, K_ = 2048, N_ = 2048;
static constexpr int KB_ = K_ / 128;  // 16 k-blocks
static constexpr int MT_ = M_ / 128;  // 32 m-tiles
static constexpr int NT_ = N_ / 128;  // 16 n-tiles
#define FP8MAX 448.0f

// ---------------- quantize x: one scale per (row, 128-k-block) ----------------
// 32 lanes per tile, each lane handles a float4.
__global__ __launch_bounds__(256) void quant_x_kernel(const float* __restrict__ x,
                                                      unsigned char* __restrict__ qx,
                                                      float* __restrict__ sx) {
  long tile = (long)blockIdx.x * 8 + (threadIdx.x >> 5);
  int lane = threadIdx.x & 31;
  f32x4 v = *(const f32x4*)(x + tile * 128 + lane * 4);
  float am = fmaxf(fmaxf(fabsf(v[0]), fabsf(v[1])), fmaxf(fabsf(v[2]), fabsf(v[3])));
#pragma unroll
  for (int off = 16; off; off >>= 1) am = fmaxf(am, __shfl_xor(am, off, 32));
  float safe = fmaxf(am, 1e-4f);
  float qs = FP8MAX / safe;   // matches reference: FP8_MAX / safe, then multiply
  int pk = 0;
  pk = __builtin_amdgcn_cvt_pk_fp8_f32(v[0] * qs, v[1] * qs, pk, false);
  pk = __builtin_amdgcn_cvt_pk_fp8_f32(v[2] * qs, v[3] * qs, pk, true);
  *(int*)(qx + tile * 128 + lane * 4) = pk;
  if (lane == 0) sx[tile] = safe / FP8MAX;   // dequant scale
}

// ---------------- quantize w: one scale per 128x128 block ----------------
// one 256-thread block per weight block; 64 floats/thread kept in registers.
__global__ __launch_bounds__(256) void quant_w_kernel(const float* __restrict__ w,
                                                      unsigned char* __restrict__ qw,
                                                      float* __restrict__ sw) {
  int b = blockIdx.x;
  int kb = b % KB_;
  int t2 = b / KB_;
  int nb = t2 % NT_;
  int e = t2 / NT_;
  int tid = threadIdx.x;
  int r = tid >> 1;             // row within block: 0..127
  int c0 = (tid & 1) * 64;      // col half: 0 or 64
  const float* base = w + ((long)(e * N_ + nb * 128 + r)) * K_ + kb * 128 + c0;
  f32x4 v[16];
  float am = 0.f;
#pragma unroll
  for (int j = 0; j < 16; ++j) {
    v[j] = *(const f32x4*)(base + j * 4);
    am = fmaxf(am, fmaxf(fmaxf(fabsf(v[j][0]), fabsf(v[j][1])),
                         fmaxf(fabsf(v[j][2]), fabsf(v[j][3]))));
  }
#pragma unroll
  for (int off = 32; off; off >>= 1) am = fmaxf(am, __shfl_xor(am, off, 64));
  __shared__ float red[4];
  if ((tid & 63) == 0) red[tid >> 6] = am;
  __syncthreads();
  am = fmaxf(fmaxf(red[0], red[1]), fmaxf(red[2], red[3]));
  float safe = fmaxf(am, 1e-6f);
  float qs = FP8MAX / safe;
  unsigned char* outp = qw + ((long)(e * N_ + nb * 128 + r)) * K_ + kb * 128 + c0;
#pragma unroll
  for (int j4 = 0; j4 < 4; ++j4) {
    uint4 pkv;
    unsigned int* pp = (unsigned int*)&pkv;
#pragma unroll
    for (int q = 0; q < 4; ++q) {
      int j = j4 * 4 + q;
      int pk = 0;
      pk = __builtin_amdgcn_cvt_pk_fp8_f32(v[j][0] * qs, v[j][1] * qs, pk, false);
      pk = __builtin_amdgcn_cvt_pk_fp8_f32(v[j][2] * qs, v[j][3] * qs, pk, true);
      pp[q] = (unsigned int)pk;
    }
    *(uint4*)(outp + j4 * 16) = pkv;
  }
  if (tid == 0) sw[(e * NT_ + nb) * KB_ + kb] = safe / FP8MAX;
}

// ---------------- grouped GEMM with per-128-block scale fold ----------------
__device__ inline void gload_lds16(const void* g, void* l) {
  __builtin_amdgcn_global_load_lds(
      (const __attribute__((address_space(1))) unsigned int*)g,
      (__attribute__((address_space(3))) unsigned int*)l, 16, 0, 0);
}

__global__ __launch_bounds__(256, 2) void gemm_kernel(
    const unsigned char* __restrict__ qx, const unsigned char* __restrict__ qw,
    const float* __restrict__ sx, const float* __restrict__ sw,
    float* __restrict__ out) {
  __shared__ unsigned char As[128 * 128];   // [row][k] fp8, 16B-chunk XOR-swizzled
  __shared__ unsigned char Bs[128 * 128];   // [n][k] fp8, same swizzle
  __shared__ float sxl[128][17];            // x scales: [row][kb], padded
  __shared__ float swl[16];                 // w scales for this n-block

  const int e = blockIdx.y;
  const int mt = blockIdx.x / NT_;
  const int nt = blockIdx.x % NT_;
  const int brow = mt * 128, bcol = nt * 128;
  const int tid = threadIdx.x;
  const int w = tid >> 6, l = tid & 63;
  const int wr = w >> 1, wc = w & 1;        // wave quadrant (2x2 of 64x64)
  const int qq = l >> 4, rl = l & 15;       // quarter-wave, lane-in-16

  // stage scales into LDS
  {
    int row = tid >> 1, half = (tid & 1) * 8;
    const float* sp = sx + ((long)(e * M_ + brow + row)) * KB_ + half;
    f32x4 s0 = *(const f32x4*)sp;
    f32x4 s1 = *(const f32x4*)(sp + 4);
#pragma unroll
    for (int j = 0; j < 4; ++j) {
      sxl[row][half + j] = s0[j];
      sxl[row][half + 4 + j] = s1[j];
    }
    if (tid < KB_) swl[tid] = sw[(e * NT_ + nt) * KB_ + tid];
  }

  f32x4 acc[4][4] = {};   // final scaled accumulator, 4x4 16x16 frags

  const unsigned char* Ab = qx + (long)(e * M_ + brow) * K_;
  const unsigned char* Bb = qw + (long)(e * N_ + bcol) * K_;
  const int lr8 = l >> 3, lc8 = l & 7;
  const int sch = (lc8 ^ lr8) * 16;   // pre-swizzled source chunk (linear LDS dest)
  const int o8 = (qq & 1) * 8;        // byte offset within 16B chunk for frag read
  const int ch = qq >> 1;             // chunk high bit from quarter

  for (int kb = 0; kb < KB_; ++kb) {
    __syncthreads();   // previous iteration's reads done before overwrite
#pragma unroll
    for (int i = 0; i < 4; ++i) {
      const int rt = i * 32 + w * 8;   // 8-row strip per wave per issue
      gload_lds16(Ab + (long)(rt + lr8) * K_ + kb * 128 + sch, As + rt * 128);
      gload_lds16(Bb + (long)(rt + lr8) * K_ + kb * 128 + sch, Bs + rt * 128);
    }
    __syncthreads();   // staged tiles visible (compiler drains vmcnt before barrier)

    // fragment loads: ds_read_b64, swizzle-corrected, ~2-way banked (free)
    long af[4][4], bf[4][4];
#pragma unroll
    for (int f = 0; f < 4; ++f) {
      const int ra = wr * 64 + f * 16 + rl;
      const int rb = wc * 64 + f * 16 + rl;
      const int rxa = ra & 7, rxb = rb & 7;
#pragma unroll
      for (int ks = 0; ks < 4; ++ks) {
        const int c = ks * 2 + ch;
        af[f][ks] = *(const long*)(As + ra * 128 + ((c ^ rxa) * 16) + o8);
        bf[f][ks] = *(const long*)(Bs + rb * 128 + ((c ^ rxb) * 16) + o8);
      }
    }

    const float swk = swl[kb];
    float sxs[4][4];
#pragma unroll
    for (int mf = 0; mf < 4; ++mf)
#pragma unroll
      for (int r = 0; r < 4; ++r)
        sxs[mf][r] = sxl[wr * 64 + mf * 16 + qq * 4 + r][kb] * swk;

#pragma unroll
    for (int mf = 0; mf < 4; ++mf)
#pragma unroll
      for (int nf = 0; nf < 4; ++nf) {
        f32x4 p = {0.f, 0.f, 0.f, 0.f};
#pragma unroll
        for (int ks = 0; ks < 4; ++ks)
          p = __builtin_amdgcn_mfma_f32_16x16x32_fp8_fp8(af[mf][ks], bf[nf][ks], p, 0, 0, 0);
#pragma unroll
        for (int r = 0; r < 4; ++r) acc[mf][nf][r] += p[r] * sxs[mf][r];
      }
  }

  // epilogue: C row = (l>>4)*4 + r, col = l&15 (m89-verified, dtype-independent)
#pragma unroll
  for (int mf = 0; mf < 4; ++mf) {
    const int m = brow + wr * 64 + mf * 16 + qq * 4;
#pragma unroll
    for (int nf = 0; nf < 4; ++nf) {
      const int n = bcol + wc * 64 + nf * 16 + rl;
      float* op = out + ((long)(e * M_ + m)) * N_ + n;
#pragma unroll
      for (int r = 0; r < 4; ++r) op[(long)r * N_] = acc[mf][nf][r];
    }
  }
}

extern "C" void kernel_launch(void* const* d_in, const int* in_sizes, int n_in,
                              void* d_out, int out_size, void* d_ws, size_t ws_size,
                              hipStream_t stream) {
  const float* x = (const float*)d_in[0];
  const float* wt = (const float*)d_in[1];
  float* out = (float*)d_out;

  unsigned char* ws = (unsigned char*)d_ws;
  unsigned char* qx = ws;                               // E*M*K bytes   = 64 MiB
  unsigned char* qw = ws + (size_t)E_ * M_ * K_;        // E*N*K bytes   = 32 MiB
  float* sx = (float*)(qw + (size_t)E_ * N_ * K_);      // E*M*KB floats =  2 MiB
  float* sw = sx + (size_t)E_ * M_ * KB_;               // E*NT*KB floats = 8 KiB

  quant_x_kernel<<<dim3((E_ * M_ * KB_) / 8), dim3(256), 0, stream>>>(x, qx, sx);
  quant_w_kernel<<<dim3(E_ * NT_ * KB_), dim3(256), 0, stream>>>(wt, qw, sw);
  gemm_kernel<<<dim3(MT_ * NT_, E_), dim3(256), 0, stream>>>(qx, qw, sx, sw, out);
}